// Round 4
// baseline (381.212 us; speedup 1.0000x reference)
//
#include <hip/hip_runtime.h>

#define BATCH   1024
#define NNODES  100
#define KDIM    640     // 5*128
#define POOL    128
#define TOPK    4
#define PDIM    2304    // 3*6*128
#define ROWF4   (KDIM / 4)          // 160 float4 per node-row
#define NKF4    (NNODES * ROWF4)    // 16000 float4 per batch row
#define RPB     2                   // batch rows per block

typedef float v4 __attribute__((ext_vector_type(4)));

// d_out layout (floats):
#define BP_OFF  0                               // batched_prompt [B, K, PDIM]
#define RS_OFF  (BATCH * TOPK * PDIM)           // reduce_sim scalar
#define SIM_OFF (RS_OFF + 1)                    // similarity [B, POOL]
#define UC_OFF  (SIM_OFF + BATCH * POOL)        // usage_counts [POOL] (as float)

// ---------------------------------------------------------------------------
// Kernel 1: normalize prompt_key, store in f4-friendly transposed layout:
//   kT[( (d>>2)*POOL + p )*4 + (d&3)] = key_norm[p][d]
// Also zeroes the atomic output regions (reduce_sim + usage_counts).
__global__ __launch_bounds__(KDIM) void k_keynorm(const float* __restrict__ pk,
                                                  float* __restrict__ kT,
                                                  float* __restrict__ out) {
    const int p = blockIdx.x;
    const int d = threadIdx.x;
    if (p == 0) {
        if (d == 0) out[RS_OFF] = 0.f;
        if (d < POOL) out[UC_OFF + d] = 0.f;
    }
    const float v = pk[(size_t)p * KDIM + d];
    float sq = v * v;
#pragma unroll
    for (int off = 32; off; off >>= 1) sq += __shfl_down(sq, off, 64);
    __shared__ float red[16];
    const int wv = d >> 6, ln = d & 63;
    if (ln == 0) red[wv] = sq;
    __syncthreads();
    if (d < 64) {
        float t = (d < 10) ? red[d] : 0.f;
#pragma unroll
        for (int off = 8; off; off >>= 1) t += __shfl_down(t, off, 64);
        if (d == 0) red[0] = t;
    }
    __syncthreads();
    const float r = rsqrtf(fmaxf(red[0], 1e-12f));
    kT[((size_t)(d >> 2) * POOL + p) * 4 + (d & 3)] = v * r;
}

// ---------------------------------------------------------------------------
// Kernel 2 (fused): one block (640 thr = 10 waves) per RPB=2 batch rows.
//   phase 1: means over nodes for both rows (plain float4 loads — L3 may be
//            hot from the harness's input restore; NT would bypass it)
//   phase 2: sim vs kT (float4 loads, L2-hot, each load feeds both rows)
//   phase 3: wave-parallel top-4, rows 0/1 on waves 0/1 concurrently
//   phase 4: gather 2x4 prompts (L2-hot reads, NT stores)
__global__ __launch_bounds__(KDIM) void k_fused(const float* __restrict__ x,
                                                const float* __restrict__ kT,
                                                const float* __restrict__ prompt,
                                                float* __restrict__ out) {
    __shared__ __align__(16) float s_red[RPB][4][ROWF4][4]; // 20 KB; reused as s_p2
    __shared__ __align__(16) float s_xn[RPB][KDIM];         // raw means
    __shared__ float s_sq[RPB][ROWF4];
    __shared__ float s_sim[RPB][POOL];
    __shared__ float s_scale[RPB];
    __shared__ int   s_idx[RPB][TOPK];

    const int b0 = blockIdx.x * RPB;
    const int t  = threadIdx.x;

    // ---- phase 1: per-row mean. thread t covers f4-col t%160, nodes t/160+4i
    {
        const v4* r0 = (const v4*)(x + (size_t)b0 * (NNODES * KDIM));
        const v4* r1 = r0 + NKF4;
        v4 a0 = (v4){0.f, 0.f, 0.f, 0.f};
        v4 a1 = (v4){0.f, 0.f, 0.f, 0.f};
#pragma unroll 5
        for (int i = 0; i < NNODES / 4; ++i) {
            a0 += r0[t + KDIM * i];              // coalesced 1 KB/wave-instr
            a1 += r1[t + KDIM * i];
        }
        const int g = t / ROWF4, c = t % ROWF4;
        *(v4*)&s_red[0][g][c][0] = a0;
        *(v4*)&s_red[1][g][c][0] = a1;
    }
    __syncthreads();
    if (t < RPB * ROWF4) {                       // 320 threads
        const int r = t / ROWF4, c = t % ROWF4;
        const v4 g0 = *(const v4*)&s_red[r][0][c][0];
        const v4 g1 = *(const v4*)&s_red[r][1][c][0];
        const v4 g2 = *(const v4*)&s_red[r][2][c][0];
        const v4 g3 = *(const v4*)&s_red[r][3][c][0];
        const v4 m = (g0 + g1 + g2 + g3) * (1.0f / NNODES);
        *(v4*)&s_xn[r][c * 4] = m;
        s_sq[r][c] = m.x * m.x + m.y * m.y + m.z * m.z + m.w * m.w;
    }
    __syncthreads();
    if (t < RPB * 64) {                          // wave r reduces row r
        const int r = t >> 6, lane = t & 63;
        float v = s_sq[r][lane] + s_sq[r][lane + 64] +
                  ((lane < 32) ? s_sq[r][lane + 128] : 0.f);
#pragma unroll
        for (int off = 32; off; off >>= 1) v += __shfl_down(v, off, 64);
        if (lane == 0) s_scale[r] = rsqrtf(fmaxf(v, 1e-12f));
    }
    __syncthreads();                 // s_red dead from here; reuse as s_p2

    // ---- phase 2: partial dots. p = t&127, d-stripe g2 = t>>7 (5 x 128 dims)
    float (*s_p2)[5][POOL] = (float (*)[5][POOL])&s_red[0][0][0][0];
    {
        const int p = t & (POOL - 1), g2 = t >> 7;
        const v4* kp = (const v4*)kT + (size_t)(g2 * 32) * POOL + p;
        const v4* x0 = (const v4*)&s_xn[0][g2 * 128];
        const v4* x1 = (const v4*)&s_xn[1][g2 * 128];
        float a0 = 0.f, a1 = 0.f;
#pragma unroll 8
        for (int i = 0; i < 32; ++i) {           // kT load feeds both rows
            const v4 kv  = kp[(size_t)i * POOL];
            const v4 xv0 = x0[i];
            const v4 xv1 = x1[i];
            a0 += kv.x * xv0.x + kv.y * xv0.y + kv.z * xv0.z + kv.w * xv0.w;
            a1 += kv.x * xv1.x + kv.y * xv1.y + kv.z * xv1.z + kv.w * xv1.w;
        }
        s_p2[0][g2][p] = a0;
        s_p2[1][g2][p] = a1;
    }
    __syncthreads();
    if (t < RPB * POOL) {                        // 256 threads
        const int r = t >> 7, p = t & (POOL - 1);
        const float sim = (s_p2[r][0][p] + s_p2[r][1][p] + s_p2[r][2][p] +
                           s_p2[r][3][p] + s_p2[r][4][p]) * s_scale[r];
        out[SIM_OFF + (size_t)(b0 + r) * POOL + p] = sim;
        s_sim[r][p] = sim;
    }
    __syncthreads();

    // ---- phase 3: wave-parallel top-4; wave r handles row r. Tie-break:
    // lower index wins (matches lax.top_k); butterfly argmax is associative.
    if (t < RPB * 64) {
        const int r = t >> 6, lane = t & 63;
        float va = s_sim[r][lane], vb = s_sim[r][lane + 64];
        const int ia = lane, ib = lane + 64;
        float rsum = 0.f;
#pragma unroll
        for (int k = 0; k < TOPK; ++k) {
            float v  = (vb > va) ? vb : va;      // tie -> a (lower index)
            int   ix = (vb > va) ? ib : ia;
#pragma unroll
            for (int off = 32; off; off >>= 1) {
                const float ov = __shfl_xor(v, off, 64);
                const int   oi = __shfl_xor(ix, off, 64);
                if (ov > v || (ov == v && oi < ix)) { v = ov; ix = oi; }
            }
            if (lane == 0) { s_idx[r][k] = ix; rsum += v; }
            if (ix == ia) va = -1e30f;
            else if (ix == ib) vb = -1e30f;
        }
        if (lane == 0) {
            atomicAdd(out + RS_OFF, rsum * (1.0f / BATCH));
            atomicAdd(out + UC_OFF + s_idx[r][0], 1.0f);
            atomicAdd(out + UC_OFF + s_idx[r][1], 1.0f);
            atomicAdd(out + UC_OFF + s_idx[r][2], 1.0f);
            atomicAdd(out + UC_OFF + s_idx[r][3], 1.0f);
        }
    }
    __syncthreads();

    // ---- phase 4: gather 2x4 prompts (pool 1.18 MB, L2-hot; NT stores keep
    // the 38 MB output stream out of L2/L3 so x stays resident)
    if (t < PDIM / 4) {                          // 576 threads, one f4 per copy
#pragma unroll
        for (int j = 0; j < RPB * TOPK; ++j) {
            const int r = j >> 2, kk = j & 3;
            const v4* src = (const v4*)(prompt + (size_t)s_idx[r][kk] * PDIM);
            v4* dst = (v4*)(out + BP_OFF + ((size_t)(b0 + r) * TOPK + kk) * PDIM);
            __builtin_nontemporal_store(src[t], &dst[t]);
        }
    }
}

// ---------------------------------------------------------------------------
extern "C" void kernel_launch(void* const* d_in, const int* in_sizes, int n_in,
                              void* d_out, int out_size, void* d_ws, size_t ws_size,
                              hipStream_t stream) {
    const float* x_embed = (const float*)d_in[0];   // [B, N, KDIM]
    const float* prompt  = (const float*)d_in[1];   // [POOL, 1, PDIM]
    const float* pkey    = (const float*)d_in[2];   // [POOL, KDIM]
    float* out = (float*)d_out;

    float* kT = (float*)d_ws;                       // KDIM * POOL floats

    k_keynorm<<<POOL,        KDIM, 0, stream>>>(pkey, kT, out);
    k_fused  <<<BATCH / RPB, KDIM, 0, stream>>>(x_embed, kT, prompt, out);
}

// Round 5
// 354.907 us; speedup vs baseline: 1.0741x; 1.0741x over previous
//
#include <hip/hip_runtime.h>

#define BATCH   1024
#define NNODES  100
#define KDIM    640     // 5*128
#define POOL    128
#define TOPK    4
#define PDIM    2304    // 3*6*128
#define ROWF4   (KDIM / 4)          // 160 float4 per node-row
#define NKF4    (NNODES * ROWF4)    // 16000 float4 per batch row
#define NTHR    320                 // 5 waves -> whole grid co-resident (20 waves/CU)

typedef float v4 __attribute__((ext_vector_type(4)));

// d_out layout (floats):
#define BP_OFF  0                               // batched_prompt [B, K, PDIM]
#define RS_OFF  (BATCH * TOPK * PDIM)           // reduce_sim scalar
#define SIM_OFF (RS_OFF + 1)                    // similarity [B, POOL]
#define UC_OFF  (SIM_OFF + BATCH * POOL)        // usage_counts [POOL] (as float)

// ---------------------------------------------------------------------------
// Kernel 1: normalize prompt_key, store in f4-friendly transposed layout:
//   kTv4[(d>>2)*POOL + p] = key_norm[p][4*(d>>2) .. +3]
// Also zeroes the atomic output regions (reduce_sim + usage_counts).
__global__ __launch_bounds__(KDIM) void k_keynorm(const float* __restrict__ pk,
                                                  float* __restrict__ kT,
                                                  float* __restrict__ out) {
    const int p = blockIdx.x;
    const int d = threadIdx.x;
    if (p == 0) {
        if (d == 0) out[RS_OFF] = 0.f;
        if (d < POOL) out[UC_OFF + d] = 0.f;
    }
    const float v = pk[(size_t)p * KDIM + d];
    float sq = v * v;
#pragma unroll
    for (int off = 32; off; off >>= 1) sq += __shfl_down(sq, off, 64);
    __shared__ float red[16];
    const int wv = d >> 6, ln = d & 63;
    if (ln == 0) red[wv] = sq;
    __syncthreads();
    if (d < 64) {
        float t = (d < 10) ? red[d] : 0.f;
#pragma unroll
        for (int off = 8; off; off >>= 1) t += __shfl_down(t, off, 64);
        if (d == 0) red[0] = t;
    }
    __syncthreads();
    const float r = rsqrtf(fmaxf(red[0], 1e-12f));
    kT[((size_t)(d >> 2) * POOL + p) * 4 + (d & 3)] = v * r;
}

// ---------------------------------------------------------------------------
// Kernel 2 (fused): one block (320 thr = 5 waves) per batch row b.
// 1024 blocks x 5 waves = 20 waves/CU -> ALL blocks co-resident: one
// continuous HBM burst; phases 2-4 of finished blocks overlap others' loads.
//   phase 1: mean over nodes (NT float4 loads; x streams once, keep L3 clean)
//   phase 2: sim vs kT (float4 L2-hot loads), scaled by rsqrt(sumsq)
//   phase 3: wave-parallel top-4 (butterfly argmax, lower-idx tie-break)
//   phase 4: gather 4 prompts (L2-hot reads, NT stores)
__global__ __launch_bounds__(NTHR, 5) void k_fused(const float* __restrict__ x,
                                                   const float* __restrict__ kT,
                                                   const float* __restrict__ prompt,
                                                   float* __restrict__ out) {
    __shared__ __align__(16) float s_part[2][ROWF4][4];   // 5 KB
    __shared__ __align__(16) float s_xn[KDIM];            // raw mean
    __shared__ float s_sq[ROWF4];
    __shared__ float s_p2[2][POOL];
    __shared__ float s_sim[POOL];
    __shared__ float s_scale;
    __shared__ int   s_idx[TOPK];

    const int b = blockIdx.x;
    const int t = threadIdx.x;

    // ---- phase 1: mean. flat idx = t + 320*i; 320 % 160 == 0 so thread t
    // always covers f4-col t%160, nodes t/160 + 2i. 50 NT loads, contiguous
    // 1 KB per wave-instr.
    {
        const v4* row = (const v4*)(x + (size_t)b * (NNODES * KDIM));
        v4 a = (v4){0.f, 0.f, 0.f, 0.f};
#pragma unroll 10
        for (int i = 0; i < NKF4 / NTHR; ++i)
            a += __builtin_nontemporal_load(&row[t + NTHR * i]);
        *(v4*)&s_part[t / ROWF4][t % ROWF4][0] = a;
    }
    __syncthreads();
    if (t < ROWF4) {
        const v4 p0 = *(const v4*)&s_part[0][t][0];
        const v4 p1 = *(const v4*)&s_part[1][t][0];
        const v4 m = (p0 + p1) * (1.0f / NNODES);
        *(v4*)&s_xn[t * 4] = m;
        s_sq[t] = m.x * m.x + m.y * m.y + m.z * m.z + m.w * m.w;
    }
    __syncthreads();
    if (t < 64) {
        float v = s_sq[t] + s_sq[t + 64] + ((t < 32) ? s_sq[t + 128] : 0.f);
#pragma unroll
        for (int off = 32; off; off >>= 1) v += __shfl_down(v, off, 64);
        if (t == 0) s_scale = rsqrtf(fmaxf(v, 1e-12f));
    }
    __syncthreads();

    // ---- phase 2: dots. threads 0..255: p = t&127, half h = t>>7 covers
    // f4-dims [h*80, h*80+80). kT loads are 1 KB/wave-instr, L2-hot.
    if (t < 2 * POOL) {
        const int p = t & (POOL - 1), h = t >> 7;
        const v4* kp = (const v4*)kT + (size_t)(h * 80) * POOL + p;
        const v4* xp = (const v4*)&s_xn[h * 80 * 4];
        float a = 0.f;
#pragma unroll 10
        for (int i = 0; i < 80; ++i) {
            const v4 kv = kp[(size_t)i * POOL];
            const v4 xv = xp[i];
            a += kv.x * xv.x + kv.y * xv.y + kv.z * xv.z + kv.w * xv.w;
        }
        s_p2[h][p] = a;
    }
    __syncthreads();
    if (t < POOL) {
        const float sim = (s_p2[0][t] + s_p2[1][t]) * s_scale;
        out[SIM_OFF + (size_t)b * POOL + t] = sim;
        s_sim[t] = sim;
    }
    __syncthreads();

    // ---- phase 3: wave-parallel top-4 on wave 0. Tie-break: lower index
    // wins (matches lax.top_k); butterfly argmax is associative.
    if (t < 64) {
        float va = s_sim[t], vb = s_sim[t + 64];
        const int ia = t, ib = t + 64;
        float rsum = 0.f;
#pragma unroll
        for (int k = 0; k < TOPK; ++k) {
            float v  = (vb > va) ? vb : va;      // tie -> a (lower index)
            int   ix = (vb > va) ? ib : ia;
#pragma unroll
            for (int off = 32; off; off >>= 1) {
                const float ov = __shfl_xor(v, off, 64);
                const int   oi = __shfl_xor(ix, off, 64);
                if (ov > v || (ov == v && oi < ix)) { v = ov; ix = oi; }
            }
            if (t == 0) { s_idx[k] = ix; rsum += v; }
            if (ix == ia) va = -1e30f;
            else if (ix == ib) vb = -1e30f;
        }
        if (t == 0) {
            atomicAdd(out + RS_OFF, rsum * (1.0f / BATCH));
            atomicAdd(out + UC_OFF + s_idx[0], 1.0f);
            atomicAdd(out + UC_OFF + s_idx[1], 1.0f);
            atomicAdd(out + UC_OFF + s_idx[2], 1.0f);
            atomicAdd(out + UC_OFF + s_idx[3], 1.0f);
        }
    }
    __syncthreads();

    // ---- phase 4: gather 4 prompts (pool 1.18 MB, L2-hot; NT stores keep
    // the 38 MB output stream from evicting hot lines)
#pragma unroll
    for (int kk = 0; kk < TOPK; ++kk) {
        const v4* src = (const v4*)(prompt + (size_t)s_idx[kk] * PDIM);
        v4* dst = (v4*)(out + BP_OFF + ((size_t)b * TOPK + kk) * PDIM);
        for (int i = t; i < PDIM / 4; i += NTHR)
            __builtin_nontemporal_store(src[i], &dst[i]);
    }
}

// ---------------------------------------------------------------------------
extern "C" void kernel_launch(void* const* d_in, const int* in_sizes, int n_in,
                              void* d_out, int out_size, void* d_ws, size_t ws_size,
                              hipStream_t stream) {
    const float* x_embed = (const float*)d_in[0];   // [B, N, KDIM]
    const float* prompt  = (const float*)d_in[1];   // [POOL, 1, PDIM]
    const float* pkey    = (const float*)d_in[2];   // [POOL, KDIM]
    float* out = (float*)d_out;

    float* kT = (float*)d_ws;                       // KDIM * POOL floats

    k_keynorm<<<POOL,  KDIM, 0, stream>>>(pkey, kT, out);
    k_fused  <<<BATCH, NTHR, 0, stream>>>(x_embed, kT, prompt, out);
}